// Round 6
// baseline (571.238 us; speedup 1.0000x reference)
//
#include <hip/hip_runtime.h>
#include <math.h>

#define WSP    7
#define HH     112
#define WWID   112
#define BB     4
#define LL     (HH*WWID)     // 12544
#define CC     128
#define NTOK   (HH*WSP)      // 784
#define NKT    13
#define NTP    832

typedef __attribute__((ext_vector_type(8))) short bf16x8;
typedef __attribute__((ext_vector_type(4))) float f32x4;

// round-to-nearest-even f32 -> bf16 (validated rounds 2-4)
__device__ inline short f2bf(float x) {
    unsigned u = __builtin_bit_cast(unsigned, x);
    unsigned r = (u + 0x7fffu + ((u >> 16) & 1u)) >> 16;
    return (short)r;
}
__device__ inline float bf2f(short h) {
    unsigned u = ((unsigned)(unsigned short)h) << 16;
    return __builtin_bit_cast(float, u);
}
// hi/lo split via RNE rounding (validated rounds 2-4): x = hi + lo + O(2^-17 x)
__device__ inline void split_rn(float x, short& hi, short& lo) {
    const short h = f2bf(x);
    hi = h;
    lo = f2bf(x - bf2f(h));
}

__global__ __launch_bounds__(256)
void attn_fused(const float* __restrict__ qkv, const float* __restrict__ cw,
                const float* __restrict__ cbv, float* __restrict__ out) {
    const int qt = blockIdx.x;           // 0..3 : 256 q-rows each
    const int g2 = blockIdx.y;           // ((b*16+wi)*4 + h)
    const int h  = g2 & 3;
    const int bw = g2 >> 2;
    const int b  = bw >> 4;
    const int wi = bw & 15;

    const int tid  = threadIdx.x;
    const int w    = tid >> 6;           // wave 0..3 -> q-rows [qbase, qbase+64)
    const int lane = tid & 63;
    const int g    = lane >> 4;          // 0..3
    const int c    = lane & 15;

    __shared__ __align__(16) short Pl[4][4][1024];   // [wave][qsub][16x64 bf16, swizzled]
    __shared__ int l_tab[NTP];                       // token -> row float-offset (l*CC)

    for (int t = tid; t < NTP; t += 256) {
        const int tc = t < NTOK ? t : NTOK - 1;
        l_tab[t] = ((tc / 7) * WWID + wi * WSP + (tc % 7)) * CC;
    }
    __syncthreads();   // only barrier in the kernel

    const int qbase = qt * 256 + w * 64;
    if (qbase >= NTOK) return;           // wave-uniform early exit (no barriers below)

    const size_t plane = (size_t)BB * LL * CC;
    const float* qp = qkv + (size_t)b * LL * CC;
    const float* kp = qp + plane;
    const float* vp = qp + 2 * plane;
    const int chb = h * 32;

    // ---- Q A-frags for 4 qsubs (hi/lo, RNE), scale folded ----
    bool valid[4];
    bf16x8 qh[4], ql[4];
    const float scale = 0.17677669529663687f;   // 32^-0.5
    #pragma unroll
    for (int qs = 0; qs < 4; ++qs) {
        valid[qs] = (qbase + qs * 16) < NTOK;
        int qrow = qbase + qs * 16 + c;
        if (qrow >= NTOK) qrow = NTOK - 1;
        const float* p = qp + l_tab[qrow] + chb + g * 8;
        const float4 a0 = *(const float4*)p;
        const float4 a1 = *(const float4*)(p + 4);
        const float av[8] = {a0.x, a0.y, a0.z, a0.w, a1.x, a1.y, a1.z, a1.w};
        #pragma unroll
        for (int j = 0; j < 8; ++j) {
            short hi, lo;
            split_rn(av[j] * scale, hi, lo);
            qh[qs][j] = hi; ql[qs][j] = lo;
        }
    }

    const bf16x8 ones = {(short)0x3F80, (short)0x3F80, (short)0x3F80, (short)0x3F80,
                         (short)0x3F80, (short)0x3F80, (short)0x3F80, (short)0x3F80};

    float m_r[4][4];
    f32x4 acc0[4], acc1[4], accl[4];
    #pragma unroll
    for (int qs = 0; qs < 4; ++qs) {
        #pragma unroll
        for (int r = 0; r < 4; ++r) m_r[qs][r] = -INFINITY;
        acc0[qs] = (f32x4){0.f, 0.f, 0.f, 0.f};
        acc1[qs] = (f32x4){0.f, 0.f, 0.f, 0.f};
        accl[qs] = (f32x4){0.f, 0.f, 0.f, 0.f};
    }

    for (int kt = 0; kt < NKT; ++kt) {
        // ---- K conversion: ONCE per wave per kt, serves 4 qsubs ----
        bf16x8 kh[4], kl[4];
        #pragma unroll
        for (int f = 0; f < 4; ++f) {
            const float* p = kp + l_tab[kt * 64 + f * 16 + c] + chb + g * 8;
            const float4 a0 = *(const float4*)p;
            const float4 a1 = *(const float4*)(p + 4);
            const float av[8] = {a0.x, a0.y, a0.z, a0.w, a1.x, a1.y, a1.z, a1.w};
            #pragma unroll
            for (int j = 0; j < 8; ++j) {
                short hi, lo;
                split_rn(av[j], hi, lo);
                kh[f][j] = hi; kl[f][j] = lo;
            }
        }

        // ---- phase A: QK^T + online softmax + P pack, per qsub ----
        #pragma unroll
        for (int qs = 0; qs < 4; ++qs) {
            if (!valid[qs]) continue;
            f32x4 sf[4];
            #pragma unroll
            for (int f = 0; f < 4; ++f) {
                f32x4 z = {0.f, 0.f, 0.f, 0.f};
                z = __builtin_amdgcn_mfma_f32_16x16x32_bf16(qh[qs], kh[f], z, 0, 0, 0);
                z = __builtin_amdgcn_mfma_f32_16x16x32_bf16(qh[qs], kl[f], z, 0, 0, 0);
                sf[f] = __builtin_amdgcn_mfma_f32_16x16x32_bf16(ql[qs], kh[f], z, 0, 0, 0);
            }

            // mask invalid keys (per-kt, validated round 3)
            #pragma unroll
            for (int f = 0; f < 4; ++f) {
                const int key = kt * 64 + f * 16 + c;
                if (key >= NTOK) {
                    sf[f][0] = -INFINITY; sf[f][1] = -INFINITY;
                    sf[f][2] = -INFINITY; sf[f][3] = -INFINITY;
                }
            }

            float rmax[4];
            #pragma unroll
            for (int r = 0; r < 4; ++r)
                rmax[r] = fmaxf(fmaxf(sf[0][r], sf[1][r]), fmaxf(sf[2][r], sf[3][r]));
            #pragma unroll
            for (int mk = 1; mk < 16; mk <<= 1)
                #pragma unroll
                for (int r = 0; r < 4; ++r)
                    rmax[r] = fmaxf(rmax[r], __shfl_xor(rmax[r], mk, 16));

            float psc[4];
            #pragma unroll
            for (int r = 0; r < 4; ++r) {
                const float mn = fmaxf(m_r[qs][r], rmax[r]);
                psc[r] = __expf(m_r[qs][r] - mn);
                m_r[qs][r] = mn;
            }

            #pragma unroll
            for (int f = 0; f < 4; ++f)
                #pragma unroll
                for (int r = 0; r < 4; ++r)
                    sf[f][r] = __expf(sf[f][r] - m_r[qs][r]);

            #pragma unroll
            for (int r = 0; r < 4; ++r) {
                acc0[qs][r] *= psc[r];
                acc1[qs][r] *= psc[r];
                accl[qs][r] *= psc[r];
            }

            // pack P (bf16 RNE, validated) to wave/qsub-private LDS, XOR-swizzled
            short* pb = &Pl[w][qs][0];
            #pragma unroll
            for (int f = 0; f < 4; ++f)
                #pragma unroll
                for (int r = 0; r < 4; ++r) {
                    const int row = g * 4 + r;
                    const int off = (f * 16 + c) * 2;
                    pb[(row * 128 + (off ^ ((row & 7) << 4))) >> 1] = f2bf(sf[f][r]);
                }
        }

        // ---- V conversion: ONCE per wave per kt, serves 4 qsubs ----
        bf16x8 vh[2][2], vl[2][2];
        #pragma unroll
        for (int s = 0; s < 2; ++s) {
            const int tb = kt * 64 + s * 32 + g * 8;
            #pragma unroll
            for (int j = 0; j < 8; ++j) {
                const int ro = l_tab[tb + j] + chb + c;
                const float x0 = vp[ro];
                const float x1 = vp[ro + 16];
                short hi, lo;
                split_rn(x0, hi, lo); vh[s][0][j] = hi; vl[s][0][j] = lo;
                split_rn(x1, hi, lo); vh[s][1][j] = hi; vl[s][1][j] = lo;
            }
        }

        // ---- phase B: PV + row-sum, per qsub ----
        #pragma unroll
        for (int qs = 0; qs < 4; ++qs) {
            if (!valid[qs]) continue;
            short* pb = &Pl[w][qs][0];
            #pragma unroll
            for (int s = 0; s < 2; ++s) {
                const int offr = s * 64 + g * 16;
                const bf16x8 pa = *(const bf16x8*)&pb[(c * 128 + (offr ^ ((c & 7) << 4))) >> 1];
                acc0[qs] = __builtin_amdgcn_mfma_f32_16x16x32_bf16(pa, vh[s][0], acc0[qs], 0, 0, 0);
                acc0[qs] = __builtin_amdgcn_mfma_f32_16x16x32_bf16(pa, vl[s][0], acc0[qs], 0, 0, 0);
                acc1[qs] = __builtin_amdgcn_mfma_f32_16x16x32_bf16(pa, vh[s][1], acc1[qs], 0, 0, 0);
                acc1[qs] = __builtin_amdgcn_mfma_f32_16x16x32_bf16(pa, vl[s][1], acc1[qs], 0, 0, 0);
                accl[qs] = __builtin_amdgcn_mfma_f32_16x16x32_bf16(pa, ones, accl[qs], 0, 0, 0);
            }
        }
    }

    // ---- fused epilogue: out = acc/l + LePE depthwise 3x3 conv + bias ----
    #pragma unroll
    for (int qs = 0; qs < 4; ++qs) {
        if (!valid[qs]) continue;
        #pragma unroll
        for (int r = 0; r < 4; ++r) {
            const int qrow = qbase + qs * 16 + g * 4 + r;
            if (qrow >= NTOK) continue;
            const int y = qrow / 7, x = qrow - y * 7;
            const int l = y * WWID + wi * WSP + x;
            const float inv = 1.0f / accl[qs][r];
            float cvs[2];
            #pragma unroll
            for (int cb2 = 0; cb2 < 2; ++cb2) {
                const int ch = chb + cb2 * 16 + c;
                float a = cbv[ch];
                #pragma unroll
                for (int dy = -1; dy <= 1; ++dy) {
                    const int yy = y + dy;
                    if (yy < 0 || yy >= HH) continue;
                    #pragma unroll
                    for (int dx = -1; dx <= 1; ++dx) {
                        const int xx = x + dx;
                        if (xx < 0 || xx >= WSP) continue;   // window-local padding
                        a += cw[ch * 9 + (dy + 1) * 3 + (dx + 1)]
                           * vp[(size_t)(yy * WWID + wi * WSP + xx) * CC + ch];
                    }
                }
                cvs[cb2] = a;
            }
            float* o = out + (size_t)b * LL * CC + (size_t)l * CC + chb;
            o[c]      = acc0[qs][r] * inv + cvs[0];
            o[16 + c] = acc1[qs][r] * inv + cvs[1];
        }
    }
}

extern "C" void kernel_launch(void* const* d_in, const int* in_sizes, int n_in,
                              void* d_out, int out_size, void* d_ws, size_t ws_size,
                              hipStream_t stream) {
    const float* qkv = (const float*)d_in[0];
    const float* cw  = (const float*)d_in[1];
    const float* cb  = (const float*)d_in[2];
    float* out = (float*)d_out;

    attn_fused<<<dim3(4, 256), 256, 0, stream>>>(qkv, cw, cb, out);
}

// Round 7
// 279.811 us; speedup vs baseline: 2.0415x; 2.0415x over previous
//
#include <hip/hip_runtime.h>
#include <math.h>

#define WSP    7
#define HH     112
#define WWID   112
#define BB     4
#define LL     (HH*WWID)     // 12544
#define CC     128
#define NTOK   (HH*WSP)      // 784
#define NKT    13
#define NTP    832

typedef __attribute__((ext_vector_type(8))) short bf16x8;
typedef __attribute__((ext_vector_type(4))) float f32x4;

// round-to-nearest-even f32 -> bf16 (validated rounds 2-4,6)
__device__ inline short f2bf(float x) {
    unsigned u = __builtin_bit_cast(unsigned, x);
    unsigned r = (u + 0x7fffu + ((u >> 16) & 1u)) >> 16;
    return (short)r;
}
__device__ inline float bf2f(short h) {
    unsigned u = ((unsigned)(unsigned short)h) << 16;
    return __builtin_bit_cast(float, u);
}
__device__ inline void split_rn(float x, short& hi, short& lo) {
    const short h = f2bf(x);
    hi = h;
    lo = f2bf(x - bf2f(h));
}

// LDS index maps (shorts). Writer and reader MUST use the same function.
// K tile: [t=0..63][ch-chunk 0..3 of 8 shorts], chunk XOR-swizzled by (t>>1)&3.
__device__ inline int k_idx(int t, int chunk) {
    return t * 32 + ((chunk ^ ((t >> 1) & 3)) << 3);
}
// V^T tile: [d=0..31][tok-chunk 0..7 of 8 shorts], chunk XOR-swizzled by d&7.
__device__ inline int v_idx(int d, int chunk) {
    return d * 64 + ((chunk ^ (d & 7)) << 3);
}

__global__ __launch_bounds__(256)
void attn_fused(const float* __restrict__ qkv, const float* __restrict__ cw,
                const float* __restrict__ cbv, float* __restrict__ out) {
    const int qt = blockIdx.x;           // 0..12 : 64 q-rows per block
    const int g2 = blockIdx.y;           // ((b*16+wi)*4 + h)
    const int h  = g2 & 3;
    const int bw = g2 >> 2;
    const int b  = bw >> 4;
    const int wi = bw & 15;

    const int tid  = threadIdx.x;
    const int w    = tid >> 6;           // wave 0..3 -> q-rows [qt*64+w*16, +16)
    const int lane = tid & 63;
    const int g    = lane >> 4;          // 0..3
    const int c    = lane & 15;

    __shared__ __align__(16) short Kh_s[64 * 32];
    __shared__ __align__(16) short Kl_s[64 * 32];
    __shared__ __align__(16) short Vh_s[32 * 64];
    __shared__ __align__(16) short Vl_s[32 * 64];
    __shared__ __align__(16) short Pl[4][1024];   // per-wave P (16x64 bf16, swizzled)
    __shared__ int l_tab[NTP];

    for (int t = tid; t < NTP; t += 256) {
        const int tc = t < NTOK ? t : NTOK - 1;
        l_tab[t] = ((tc / 7) * WWID + wi * WSP + (tc % 7)) * CC;
    }
    __syncthreads();

    const size_t plane = (size_t)BB * LL * CC;
    const float* qp = qkv + (size_t)b * LL * CC;
    const float* kp = qp + plane;
    const float* vp = qp + 2 * plane;
    const int chb = h * 32;

    const bool qvalid = (qt * 64 + w * 16) < NTOK;   // wave-uniform

    // ---- Q A-frag (hi/lo RNE), scale folded ----
    bf16x8 qh, ql;
    {
        int qrow = qt * 64 + w * 16 + c;
        if (qrow >= NTOK) qrow = NTOK - 1;
        const float* p = qp + l_tab[qrow] + chb + g * 8;
        const float4 a0 = *(const float4*)p;
        const float4 a1 = *(const float4*)(p + 4);
        const float av[8] = {a0.x, a0.y, a0.z, a0.w, a1.x, a1.y, a1.z, a1.w};
        const float scale = 0.17677669529663687f;   // 32^-0.5
        #pragma unroll
        for (int j = 0; j < 8; ++j) {
            short hi, lo;
            split_rn(av[j] * scale, hi, lo);
            qh[j] = hi; ql[j] = lo;
        }
    }

    const bf16x8 ones = {(short)0x3F80, (short)0x3F80, (short)0x3F80, (short)0x3F80,
                         (short)0x3F80, (short)0x3F80, (short)0x3F80, (short)0x3F80};

    float m_r[4];
    f32x4 acc0 = {0.f, 0.f, 0.f, 0.f};
    f32x4 acc1 = {0.f, 0.f, 0.f, 0.f};
    f32x4 accl = {0.f, 0.f, 0.f, 0.f};
    #pragma unroll
    for (int r = 0; r < 4; ++r) m_r[r] = -INFINITY;

    short* pb = &Pl[w][0];

    // staging roles (fixed per thread)
    const int st_t  = tid >> 2;    // K: token 0..63
    const int st_dg = tid & 3;     // K: 8-ch chunk 0..3
    const int st_d  = tid & 31;    // V: channel 0..31
    const int st_tg = tid >> 5;    // V: token-chunk 0..7

    for (int kt = 0; kt < NKT; ++kt) {
        __syncthreads();   // previous iteration's frag reads complete

        // ---- stage K (hi/lo) cooperatively: 8 ch of one token per thread ----
        {
            const float* p = kp + l_tab[kt * 64 + st_t] + chb + st_dg * 8;
            const float4 a0 = *(const float4*)p;
            const float4 a1 = *(const float4*)(p + 4);
            const float av[8] = {a0.x, a0.y, a0.z, a0.w, a1.x, a1.y, a1.z, a1.w};
            bf16x8 hv, lv;
            #pragma unroll
            for (int j = 0; j < 8; ++j) {
                short hi, lo;
                split_rn(av[j], hi, lo);
                hv[j] = hi; lv[j] = lo;
            }
            const int o = k_idx(st_t, st_dg);
            *(bf16x8*)&Kh_s[o] = hv;
            *(bf16x8*)&Kl_s[o] = lv;
        }
        // ---- stage V^T (hi/lo) cooperatively: 8 tokens of one channel per thread ----
        {
            bf16x8 hv, lv;
            #pragma unroll
            for (int j = 0; j < 8; ++j) {
                const float x = vp[l_tab[kt * 64 + st_tg * 8 + j] + chb + st_d];
                short hi, lo;
                split_rn(x, hi, lo);
                hv[j] = hi; lv[j] = lo;
            }
            const int o = v_idx(st_d, st_tg);
            *(bf16x8*)&Vh_s[o] = hv;
            *(bf16x8*)&Vl_s[o] = lv;
        }
        __syncthreads();

        if (qvalid) {
            // ---- K frags from LDS ----
            bf16x8 kh[4], kl[4];
            #pragma unroll
            for (int f = 0; f < 4; ++f) {
                const int o = k_idx(f * 16 + c, g);
                kh[f] = *(const bf16x8*)&Kh_s[o];
                kl[f] = *(const bf16x8*)&Kl_s[o];
            }

            // ---- QK^T ----
            f32x4 sf[4];
            #pragma unroll
            for (int f = 0; f < 4; ++f) {
                f32x4 z = {0.f, 0.f, 0.f, 0.f};
                z = __builtin_amdgcn_mfma_f32_16x16x32_bf16(qh, kh[f], z, 0, 0, 0);
                z = __builtin_amdgcn_mfma_f32_16x16x32_bf16(qh, kl[f], z, 0, 0, 0);
                sf[f] = __builtin_amdgcn_mfma_f32_16x16x32_bf16(ql, kh[f], z, 0, 0, 0);
            }

            // mask invalid keys (only last tile can have key >= NTOK; provable)
            if (kt == NKT - 1) {
                #pragma unroll
                for (int f = 0; f < 4; ++f) {
                    const int key = kt * 64 + f * 16 + c;
                    if (key >= NTOK) {
                        sf[f][0] = -INFINITY; sf[f][1] = -INFINITY;
                        sf[f][2] = -INFINITY; sf[f][3] = -INFINITY;
                    }
                }
            }

            // ---- online softmax ----
            float rmax[4];
            #pragma unroll
            for (int r = 0; r < 4; ++r)
                rmax[r] = fmaxf(fmaxf(sf[0][r], sf[1][r]), fmaxf(sf[2][r], sf[3][r]));
            #pragma unroll
            for (int mk = 1; mk < 16; mk <<= 1)
                #pragma unroll
                for (int r = 0; r < 4; ++r)
                    rmax[r] = fmaxf(rmax[r], __shfl_xor(rmax[r], mk, 16));

            float psc[4];
            #pragma unroll
            for (int r = 0; r < 4; ++r) {
                const float mn = fmaxf(m_r[r], rmax[r]);
                psc[r] = __expf(m_r[r] - mn);
                m_r[r] = mn;
            }

            #pragma unroll
            for (int f = 0; f < 4; ++f)
                #pragma unroll
                for (int r = 0; r < 4; ++r)
                    sf[f][r] = __expf(sf[f][r] - m_r[r]);

            #pragma unroll
            for (int r = 0; r < 4; ++r) {
                acc0[r] *= psc[r];
                acc1[r] *= psc[r];
                accl[r] *= psc[r];
            }

            // ---- pack P (bf16 RNE) to wave-private LDS, XOR-swizzled ----
            #pragma unroll
            for (int f = 0; f < 4; ++f)
                #pragma unroll
                for (int r = 0; r < 4; ++r) {
                    const int row = g * 4 + r;
                    const int off = (f * 16 + c) * 2;
                    pb[(row * 128 + (off ^ ((row & 7) << 4))) >> 1] = f2bf(sf[f][r]);
                }

            // ---- PV: A = P (LDS), B = V^T (LDS) ----
            #pragma unroll
            for (int s = 0; s < 2; ++s) {
                const int offr = s * 64 + g * 16;
                const bf16x8 pa = *(const bf16x8*)&pb[(c * 128 + (offr ^ ((c & 7) << 4))) >> 1];
                #pragma unroll
                for (int cb = 0; cb < 2; ++cb) {
                    const int o = v_idx(cb * 16 + c, s * 4 + g);
                    const bf16x8 vh = *(const bf16x8*)&Vh_s[o];
                    const bf16x8 vl = *(const bf16x8*)&Vl_s[o];
                    if (cb == 0) {
                        acc0 = __builtin_amdgcn_mfma_f32_16x16x32_bf16(pa, vh, acc0, 0, 0, 0);
                        acc0 = __builtin_amdgcn_mfma_f32_16x16x32_bf16(pa, vl, acc0, 0, 0, 0);
                    } else {
                        acc1 = __builtin_amdgcn_mfma_f32_16x16x32_bf16(pa, vh, acc1, 0, 0, 0);
                        acc1 = __builtin_amdgcn_mfma_f32_16x16x32_bf16(pa, vl, acc1, 0, 0, 0);
                    }
                }
                accl = __builtin_amdgcn_mfma_f32_16x16x32_bf16(pa, ones, accl, 0, 0, 0);
            }
        }
    }

    // ---- fused epilogue: out = acc/l + LePE depthwise 3x3 conv + bias ----
    if (qvalid) {
        #pragma unroll
        for (int r = 0; r < 4; ++r) {
            const int qrow = qt * 64 + w * 16 + g * 4 + r;
            if (qrow >= NTOK) continue;
            const int y = qrow / 7, x = qrow - y * 7;
            const int l = y * WWID + wi * WSP + x;
            const float inv = 1.0f / accl[r];
            float cvs[2];
            #pragma unroll
            for (int cb2 = 0; cb2 < 2; ++cb2) {
                const int ch = chb + cb2 * 16 + c;
                float a = cbv[ch];
                #pragma unroll
                for (int dy = -1; dy <= 1; ++dy) {
                    const int yy = y + dy;
                    if (yy < 0 || yy >= HH) continue;
                    #pragma unroll
                    for (int dx = -1; dx <= 1; ++dx) {
                        const int xx = x + dx;
                        if (xx < 0 || xx >= WSP) continue;   // window-local padding
                        a += cw[ch * 9 + (dy + 1) * 3 + (dx + 1)]
                           * vp[(size_t)(yy * WWID + wi * WSP + xx) * CC + ch];
                    }
                }
                cvs[cb2] = a;
            }
            float* o = out + (size_t)b * LL * CC + (size_t)l * CC + chb;
            o[c]      = acc0[r] * inv + cvs[0];
            o[16 + c] = acc1[r] * inv + cvs[1];
        }
    }
}

extern "C" void kernel_launch(void* const* d_in, const int* in_sizes, int n_in,
                              void* d_out, int out_size, void* d_ws, size_t ws_size,
                              hipStream_t stream) {
    const float* qkv = (const float*)d_in[0];
    const float* cw  = (const float*)d_in[1];
    const float* cb  = (const float*)d_in[2];
    float* out = (float*)d_out;

    attn_fused<<<dim3(NKT, 256), 256, 0, stream>>>(qkv, cw, cb, out);
}

// Round 8
// 257.248 us; speedup vs baseline: 2.2206x; 1.0877x over previous
//
#include <hip/hip_runtime.h>
#include <math.h>

#define WSP    7
#define HH     112
#define WWID   112
#define BB     4
#define LL     (HH*WWID)     // 12544
#define CC     128
#define NTOK   (HH*WSP)      // 784
#define NKT    13
#define NTP    832

typedef _Float16 f16x8 __attribute__((ext_vector_type(8)));
typedef __attribute__((ext_vector_type(4))) float f32x4;

// LDS index maps (f16 elements). Writer and reader MUST use the same function.
// K tile: [t=0..63][ch-chunk 0..3 of 8 halves], chunk XOR-swizzled by (t>>1)&3.
__device__ inline int k_idx(int t, int chunk) {
    return t * 32 + ((chunk ^ ((t >> 1) & 3)) << 3);
}
// V^T tile: [d=0..31][tok-chunk 0..7 of 8 halves], chunk XOR-swizzled by d&7.
__device__ inline int v_idx(int d, int chunk) {
    return d * 64 + ((chunk ^ (d & 7)) << 3);
}

__global__ __launch_bounds__(256)
void attn_fused(const float* __restrict__ qkv, const float* __restrict__ cw,
                const float* __restrict__ cbv, float* __restrict__ out) {
    const int qt = blockIdx.x;           // 0..12 : 64 q-rows per block
    const int g2 = blockIdx.y;           // ((b*16+wi)*4 + h)
    const int h  = g2 & 3;
    const int bw = g2 >> 2;
    const int b  = bw >> 4;
    const int wi = bw & 15;

    const int tid  = threadIdx.x;
    const int w    = tid >> 6;           // wave 0..3 -> q-rows [qt*64+w*16, +16)
    const int lane = tid & 63;
    const int g    = lane >> 4;          // 0..3
    const int c    = lane & 15;

    __shared__ __align__(16) _Float16 K_s[64 * 32];
    __shared__ __align__(16) _Float16 V_s[32 * 64];
    __shared__ __align__(16) _Float16 Pl[4][1024];   // per-wave P (16x64, swizzled)
    __shared__ int l_tab[NTP];

    for (int t = tid; t < NTP; t += 256) {
        const int tc = t < NTOK ? t : NTOK - 1;
        l_tab[t] = ((tc / 7) * WWID + wi * WSP + (tc % 7)) * CC;
    }
    __syncthreads();

    const size_t plane = (size_t)BB * LL * CC;
    const float* qp = qkv + (size_t)b * LL * CC;
    const float* kp = qp + plane;
    const float* vp = qp + 2 * plane;
    const int chb = h * 32;

    const bool qvalid = (qt * 64 + w * 16) < NTOK;   // wave-uniform

    // ---- Q A-frag (f16), scale folded ----
    f16x8 qf;
    {
        int qrow = qt * 64 + w * 16 + c;
        if (qrow >= NTOK) qrow = NTOK - 1;
        const float* p = qp + l_tab[qrow] + chb + g * 8;
        const float4 a0 = *(const float4*)p;
        const float4 a1 = *(const float4*)(p + 4);
        const float av[8] = {a0.x, a0.y, a0.z, a0.w, a1.x, a1.y, a1.z, a1.w};
        const float scale = 0.17677669529663687f;   // 32^-0.5
        #pragma unroll
        for (int j = 0; j < 8; ++j) qf[j] = (_Float16)(av[j] * scale);
    }

    const f16x8 ones = {(_Float16)1.f, (_Float16)1.f, (_Float16)1.f, (_Float16)1.f,
                        (_Float16)1.f, (_Float16)1.f, (_Float16)1.f, (_Float16)1.f};

    float m_r[4];
    f32x4 acc0 = {0.f, 0.f, 0.f, 0.f};
    f32x4 acc1 = {0.f, 0.f, 0.f, 0.f};
    f32x4 accl = {0.f, 0.f, 0.f, 0.f};
    #pragma unroll
    for (int r = 0; r < 4; ++r) m_r[r] = -INFINITY;

    _Float16* pb = &Pl[w][0];

    // staging roles (fixed per thread)
    const int st_t  = tid >> 2;    // K: token 0..63
    const int st_dg = tid & 3;     // K: 8-ch chunk 0..3
    const int st_d  = tid & 31;    // V: channel 0..31
    const int st_tg = tid >> 5;    // V: token-chunk 0..7

    for (int kt = 0; kt < NKT; ++kt) {
        __syncthreads();   // previous iteration's frag reads complete

        // ---- stage K (f16) cooperatively: 8 ch of one token per thread ----
        {
            const float* p = kp + l_tab[kt * 64 + st_t] + chb + st_dg * 8;
            const float4 a0 = *(const float4*)p;
            const float4 a1 = *(const float4*)(p + 4);
            const float av[8] = {a0.x, a0.y, a0.z, a0.w, a1.x, a1.y, a1.z, a1.w};
            f16x8 hv;
            #pragma unroll
            for (int j = 0; j < 8; ++j) hv[j] = (_Float16)av[j];
            *(f16x8*)&K_s[k_idx(st_t, st_dg)] = hv;
        }
        // ---- stage V^T (f16) cooperatively: 8 tokens of one channel per thread ----
        {
            f16x8 hv;
            #pragma unroll
            for (int j = 0; j < 8; ++j)
                hv[j] = (_Float16)vp[l_tab[kt * 64 + st_tg * 8 + j] + chb + st_d];
            *(f16x8*)&V_s[v_idx(st_d, st_tg)] = hv;
        }
        __syncthreads();

        if (qvalid) {
            // ---- K frags from LDS ----
            f16x8 kf[4];
            #pragma unroll
            for (int f = 0; f < 4; ++f)
                kf[f] = *(const f16x8*)&K_s[k_idx(f * 16 + c, g)];

            // ---- QK^T: one f16 MFMA per 16-key group ----
            f32x4 sf[4];
            #pragma unroll
            for (int f = 0; f < 4; ++f) {
                f32x4 z = {0.f, 0.f, 0.f, 0.f};
                sf[f] = __builtin_amdgcn_mfma_f32_16x16x32_f16(qf, kf[f], z, 0, 0, 0);
            }

            // mask invalid keys (only last tile can have key >= NTOK; provable)
            if (kt == NKT - 1) {
                #pragma unroll
                for (int f = 0; f < 4; ++f) {
                    const int key = kt * 64 + f * 16 + c;
                    if (key >= NTOK) {
                        sf[f][0] = -INFINITY; sf[f][1] = -INFINITY;
                        sf[f][2] = -INFINITY; sf[f][3] = -INFINITY;
                    }
                }
            }

            // ---- online softmax ----
            float rmax[4];
            #pragma unroll
            for (int r = 0; r < 4; ++r)
                rmax[r] = fmaxf(fmaxf(sf[0][r], sf[1][r]), fmaxf(sf[2][r], sf[3][r]));
            #pragma unroll
            for (int mk = 1; mk < 16; mk <<= 1)
                #pragma unroll
                for (int r = 0; r < 4; ++r)
                    rmax[r] = fmaxf(rmax[r], __shfl_xor(rmax[r], mk, 16));

            float psc[4];
            #pragma unroll
            for (int r = 0; r < 4; ++r) {
                const float mn = fmaxf(m_r[r], rmax[r]);
                psc[r] = __expf(m_r[r] - mn);
                m_r[r] = mn;
            }

            #pragma unroll
            for (int f = 0; f < 4; ++f)
                #pragma unroll
                for (int r = 0; r < 4; ++r)
                    sf[f][r] = __expf(sf[f][r] - m_r[r]);

            #pragma unroll
            for (int r = 0; r < 4; ++r) {
                acc0[r] *= psc[r];
                acc1[r] *= psc[r];
                accl[r] *= psc[r];
            }

            // ---- pack P (f16) to wave-private LDS, XOR-swizzled ----
            #pragma unroll
            for (int f = 0; f < 4; ++f)
                #pragma unroll
                for (int r = 0; r < 4; ++r) {
                    const int row = g * 4 + r;
                    const int off = (f * 16 + c) * 2;
                    pb[(row * 128 + (off ^ ((row & 7) << 4))) >> 1] = (_Float16)sf[f][r];
                }

            // ---- PV: A = P (LDS), B = V^T (LDS), f16 single-pass ----
            #pragma unroll
            for (int s = 0; s < 2; ++s) {
                const int offr = s * 64 + g * 16;
                const f16x8 pa = *(const f16x8*)&pb[(c * 128 + (offr ^ ((c & 7) << 4))) >> 1];
                const f16x8 v0 = *(const f16x8*)&V_s[v_idx(c,      s * 4 + g)];
                const f16x8 v1 = *(const f16x8*)&V_s[v_idx(16 + c, s * 4 + g)];
                acc0 = __builtin_amdgcn_mfma_f32_16x16x32_f16(pa, v0, acc0, 0, 0, 0);
                acc1 = __builtin_amdgcn_mfma_f32_16x16x32_f16(pa, v1, acc1, 0, 0, 0);
                accl = __builtin_amdgcn_mfma_f32_16x16x32_f16(pa, ones, accl, 0, 0, 0);
            }
        }
    }

    // ---- fused epilogue: out = acc/l + LePE depthwise 3x3 conv + bias ----
    if (qvalid) {
        #pragma unroll
        for (int r = 0; r < 4; ++r) {
            const int qrow = qt * 64 + w * 16 + g * 4 + r;
            if (qrow >= NTOK) continue;
            const int y = qrow / 7, x = qrow - y * 7;
            const int l = y * WWID + wi * WSP + x;
            const float inv = 1.0f / accl[r];
            float cvs[2];
            #pragma unroll
            for (int cb2 = 0; cb2 < 2; ++cb2) {
                const int ch = chb + cb2 * 16 + c;
                float a = cbv[ch];
                #pragma unroll
                for (int dy = -1; dy <= 1; ++dy) {
                    const int yy = y + dy;
                    if (yy < 0 || yy >= HH) continue;
                    #pragma unroll
                    for (int dx = -1; dx <= 1; ++dx) {
                        const int xx = x + dx;
                        if (xx < 0 || xx >= WSP) continue;   // window-local padding
                        a += cw[ch * 9 + (dy + 1) * 3 + (dx + 1)]
                           * vp[(size_t)(yy * WWID + wi * WSP + xx) * CC + ch];
                    }
                }
                cvs[cb2] = a;
            }
            float* o = out + (size_t)b * LL * CC + (size_t)l * CC + chb;
            o[c]      = acc0[r] * inv + cvs[0];
            o[16 + c] = acc1[r] * inv + cvs[1];
        }
    }
}

extern "C" void kernel_launch(void* const* d_in, const int* in_sizes, int n_in,
                              void* d_out, int out_size, void* d_ws, size_t ws_size,
                              hipStream_t stream) {
    const float* qkv = (const float*)d_in[0];
    const float* cw  = (const float*)d_in[1];
    const float* cb  = (const float*)d_in[2];
    float* out = (float*)d_out;

    attn_fused<<<dim3(NKT, 256), 256, 0, stream>>>(qkv, cw, cb, out);
}

// Round 9
// 242.805 us; speedup vs baseline: 2.3527x; 1.0595x over previous
//
#include <hip/hip_runtime.h>
#include <math.h>

#define WSP    7
#define HH     112
#define WWID   112
#define BB     4
#define LL     (HH*WWID)     // 12544
#define CC     128
#define NTOK   (HH*WSP)      // 784
#define NKT    13
#define NTP    832

typedef _Float16 f16x8 __attribute__((ext_vector_type(8)));
typedef __attribute__((ext_vector_type(4))) float f32x4;

// LDS index maps (f16 elements). Writer and reader MUST use the same function.
// K tile: [t=0..63][ch-chunk 0..3 of 8 halves], chunk XOR-swizzled by (t>>1)&3.
__device__ inline int k_idx(int t, int chunk) {
    return t * 32 + ((chunk ^ ((t >> 1) & 3)) << 3);
}
// V^T tile: [d=0..31][tok-chunk 0..7 of 8 halves], chunk XOR-swizzled by d&7.
__device__ inline int v_idx(int d, int chunk) {
    return d * 64 + ((chunk ^ (d & 7)) << 3);
}

__global__ __launch_bounds__(256)
void attn_fused(const float* __restrict__ qkv, const float* __restrict__ cw,
                const float* __restrict__ cbv, float* __restrict__ out) {
    const int qt = blockIdx.x;           // 0..12 : 64 q-rows per block
    const int g2 = blockIdx.y;           // ((b*16+wi)*4 + h)
    const int h  = g2 & 3;
    const int bw = g2 >> 2;
    const int b  = bw >> 4;
    const int wi = bw & 15;

    const int tid  = threadIdx.x;
    const int w    = tid >> 6;           // wave 0..3 -> q-rows [qt*64+w*16, +16)
    const int lane = tid & 63;
    const int g    = lane >> 4;          // 0..3
    const int c    = lane & 15;

    __shared__ __align__(16) _Float16 K_s[2][64 * 32];   // double-buffered
    __shared__ __align__(16) _Float16 V_s[2][32 * 64];
    __shared__ __align__(16) _Float16 Pl[4][1024];       // per-wave P (16x64, swizzled)
    __shared__ unsigned short l_tab[NTP];                // token -> row index l (use <<7)

    for (int t = tid; t < NTP; t += 256) {
        const int tc = t < NTOK ? t : NTOK - 1;
        l_tab[t] = (unsigned short)((tc / 7) * WWID + wi * WSP + (tc % 7));
    }
    __syncthreads();

    const size_t plane = (size_t)BB * LL * CC;
    const float* qp = qkv + (size_t)b * LL * CC;
    const float* kp = qp + plane;
    const float* vp = qp + 2 * plane;
    const int chb = h * 32;

    const bool qvalid = (qt * 64 + w * 16) < NTOK;   // wave-uniform

    // ---- Q A-frag (f16), scale folded ----
    f16x8 qf;
    {
        int qrow = qt * 64 + w * 16 + c;
        if (qrow >= NTOK) qrow = NTOK - 1;
        const float* p = qp + ((int)l_tab[qrow] << 7) + chb + g * 8;
        const float4 a0 = *(const float4*)p;
        const float4 a1 = *(const float4*)(p + 4);
        const float av[8] = {a0.x, a0.y, a0.z, a0.w, a1.x, a1.y, a1.z, a1.w};
        const float scale = 0.17677669529663687f;   // 32^-0.5
        #pragma unroll
        for (int j = 0; j < 8; ++j) qf[j] = (_Float16)(av[j] * scale);
    }

    const f16x8 ones = {(_Float16)1.f, (_Float16)1.f, (_Float16)1.f, (_Float16)1.f,
                        (_Float16)1.f, (_Float16)1.f, (_Float16)1.f, (_Float16)1.f};

    float m_r[4];
    f32x4 acc0 = {0.f, 0.f, 0.f, 0.f};
    f32x4 acc1 = {0.f, 0.f, 0.f, 0.f};
    f32x4 accl = {0.f, 0.f, 0.f, 0.f};
    #pragma unroll
    for (int r = 0; r < 4; ++r) m_r[r] = -INFINITY;

    _Float16* pb = &Pl[w][0];

    // staging roles (fixed per thread)
    const int st_t  = tid >> 2;    // K: token 0..63
    const int st_dg = tid & 3;     // K: 8-ch chunk 0..3
    const int st_d  = tid & 31;    // V: channel 0..31
    const int st_tg = tid >> 5;    // V: token-chunk 0..7

    // ---- prologue: issue loads for tile 0 ----
    float4 ka, kb;
    float va[8];
    {
        const float* p = kp + ((int)l_tab[st_t] << 7) + chb + st_dg * 8;
        ka = *(const float4*)p;
        kb = *(const float4*)(p + 4);
        #pragma unroll
        for (int j = 0; j < 8; ++j)
            va[j] = vp[((int)l_tab[st_tg * 8 + j] << 7) + chb + st_d];
    }

    for (int kt = 0; kt < NKT; ++kt) {
        const int bi = kt & 1;

        // ---- convert current regs -> LDS buf[bi] ----
        {
            const float av[8] = {ka.x, ka.y, ka.z, ka.w, kb.x, kb.y, kb.z, kb.w};
            f16x8 hv;
            #pragma unroll
            for (int j = 0; j < 8; ++j) hv[j] = (_Float16)av[j];
            *(f16x8*)&K_s[bi][k_idx(st_t, st_dg)] = hv;
            f16x8 vv;
            #pragma unroll
            for (int j = 0; j < 8; ++j) vv[j] = (_Float16)va[j];
            *(f16x8*)&V_s[bi][v_idx(st_d, st_tg)] = vv;
        }

        // ---- prefetch next tile into the (now free) regs; stays in flight ----
        if (kt + 1 < NKT) {
            const float* p = kp + ((int)l_tab[(kt + 1) * 64 + st_t] << 7) + chb + st_dg * 8;
            ka = *(const float4*)p;
            kb = *(const float4*)(p + 4);
            #pragma unroll
            for (int j = 0; j < 8; ++j)
                va[j] = vp[((int)l_tab[(kt + 1) * 64 + st_tg * 8 + j] << 7) + chb + st_d];
        }

        __syncthreads();   // buf[bi] ready; also separates next iter's writes (WAR)

        if (qvalid) {
            // ---- K frags from LDS ----
            f16x8 kf[4];
            #pragma unroll
            for (int f = 0; f < 4; ++f)
                kf[f] = *(const f16x8*)&K_s[bi][k_idx(f * 16 + c, g)];

            // ---- QK^T: one f16 MFMA per 16-key group ----
            f32x4 sf[4];
            #pragma unroll
            for (int f = 0; f < 4; ++f) {
                f32x4 z = {0.f, 0.f, 0.f, 0.f};
                sf[f] = __builtin_amdgcn_mfma_f32_16x16x32_f16(qf, kf[f], z, 0, 0, 0);
            }

            // mask invalid keys (only last tile can have key >= NTOK; provable)
            if (kt == NKT - 1) {
                #pragma unroll
                for (int f = 0; f < 4; ++f) {
                    const int key = kt * 64 + f * 16 + c;
                    if (key >= NTOK) {
                        sf[f][0] = -INFINITY; sf[f][1] = -INFINITY;
                        sf[f][2] = -INFINITY; sf[f][3] = -INFINITY;
                    }
                }
            }

            // ---- online softmax ----
            float rmax[4];
            #pragma unroll
            for (int r = 0; r < 4; ++r)
                rmax[r] = fmaxf(fmaxf(sf[0][r], sf[1][r]), fmaxf(sf[2][r], sf[3][r]));
            #pragma unroll
            for (int mk = 1; mk < 16; mk <<= 1)
                #pragma unroll
                for (int r = 0; r < 4; ++r)
                    rmax[r] = fmaxf(rmax[r], __shfl_xor(rmax[r], mk, 16));

            float psc[4];
            #pragma unroll
            for (int r = 0; r < 4; ++r) {
                const float mn = fmaxf(m_r[r], rmax[r]);
                psc[r] = __expf(m_r[r] - mn);
                m_r[r] = mn;
            }

            #pragma unroll
            for (int f = 0; f < 4; ++f)
                #pragma unroll
                for (int r = 0; r < 4; ++r)
                    sf[f][r] = __expf(sf[f][r] - m_r[r]);

            #pragma unroll
            for (int r = 0; r < 4; ++r) {
                acc0[r] *= psc[r];
                acc1[r] *= psc[r];
                accl[r] *= psc[r];
            }

            // ---- pack P (f16) to wave-private LDS, XOR-swizzled ----
            #pragma unroll
            for (int f = 0; f < 4; ++f)
                #pragma unroll
                for (int r = 0; r < 4; ++r) {
                    const int row = g * 4 + r;
                    const int off = (f * 16 + c) * 2;
                    pb[(row * 128 + (off ^ ((row & 7) << 4))) >> 1] = (_Float16)sf[f][r];
                }

            // ---- PV: A = P (LDS), B = V^T (LDS) ----
            #pragma unroll
            for (int s = 0; s < 2; ++s) {
                const int offr = s * 64 + g * 16;
                const f16x8 pa = *(const f16x8*)&pb[(c * 128 + (offr ^ ((c & 7) << 4))) >> 1];
                const f16x8 v0 = *(const f16x8*)&V_s[bi][v_idx(c,      s * 4 + g)];
                const f16x8 v1 = *(const f16x8*)&V_s[bi][v_idx(16 + c, s * 4 + g)];
                acc0 = __builtin_amdgcn_mfma_f32_16x16x32_f16(pa, v0, acc0, 0, 0, 0);
                acc1 = __builtin_amdgcn_mfma_f32_16x16x32_f16(pa, v1, acc1, 0, 0, 0);
                accl = __builtin_amdgcn_mfma_f32_16x16x32_f16(pa, ones, accl, 0, 0, 0);
            }
        }
    }

    // ---- fused epilogue: out = acc/l + LePE depthwise 3x3 conv + bias ----
    if (qvalid) {
        #pragma unroll
        for (int r = 0; r < 4; ++r) {
            const int qrow = qt * 64 + w * 16 + g * 4 + r;
            if (qrow >= NTOK) continue;
            const int y = qrow / 7, x = qrow - y * 7;
            const int l = y * WWID + wi * WSP + x;
            const float inv = 1.0f / accl[r];
            float cvs[2];
            #pragma unroll
            for (int cb2 = 0; cb2 < 2; ++cb2) {
                const int ch = chb + cb2 * 16 + c;
                float a = cbv[ch];
                #pragma unroll
                for (int dy = -1; dy <= 1; ++dy) {
                    const int yy = y + dy;
                    if (yy < 0 || yy >= HH) continue;
                    #pragma unroll
                    for (int dx = -1; dx <= 1; ++dx) {
                        const int xx = x + dx;
                        if (xx < 0 || xx >= WSP) continue;   // window-local padding
                        a += cw[ch * 9 + (dy + 1) * 3 + (dx + 1)]
                           * vp[(size_t)(yy * WWID + wi * WSP + xx) * CC + ch];
                    }
                }
                cvs[cb2] = a;
            }
            float* o = out + (size_t)b * LL * CC + (size_t)l * CC + chb;
            o[c]      = acc0[r] * inv + cvs[0];
            o[16 + c] = acc1[r] * inv + cvs[1];
        }
    }
}

extern "C" void kernel_launch(void* const* d_in, const int* in_sizes, int n_in,
                              void* d_out, int out_size, void* d_ws, size_t ws_size,
                              hipStream_t stream) {
    const float* qkv = (const float*)d_in[0];
    const float* cw  = (const float*)d_in[1];
    const float* cb  = (const float*)d_in[2];
    float* out = (float*)d_out;

    attn_fused<<<dim3(NKT, 256), 256, 0, stream>>>(qkv, cw, cb, out);
}